// Round 10
// baseline (433.374 us; speedup 1.0000x reference)
//
#include <hip/hip_runtime.h>
#include <hip/hip_bf16.h>

typedef __attribute__((ext_vector_type(8))) short bf16x8;
typedef __attribute__((ext_vector_type(4))) float f32x4;

#define NPB 32          // nodes per bucket (dst>>5)
#define BCAP 768        // total record capacity per bucket in k_build LDS (~512 +11 sigma)
#define NSHARD 8        // write shards (~XCDs): blockIdx & 7
#define SCAP 160        // per-(shard,bucket) capacity (load ~64, +12 sigma)
#define CURSTRIDE 16    // ints: one cursor per 64B line

// ---------------- helpers ----------------

static __device__ __forceinline__ unsigned short f2bf(float f) {
    unsigned int u = __float_as_uint(f);
    unsigned int r = (u + 0x7fffu + ((u >> 16) & 1u)) >> 16;  // RNE
    return (unsigned short)r;
}
static __device__ __forceinline__ float bflo(unsigned int v) {
    return __uint_as_float(v << 16);
}
static __device__ __forceinline__ float bfhi(unsigned int v) {
    return __uint_as_float(v & 0xffff0000u);
}

// ---------------- CSR build: sharded bucketed multisplit ----------------

__global__ void k_bin(const int* __restrict__ src, const int* __restrict__ dst, int E,
                      int NB, int* __restrict__ scur, unsigned* __restrict__ recs) {
    int e = blockIdx.x * blockDim.x + threadIdx.x;
    const int shard = blockIdx.x & (NSHARD - 1);
    if (e < E) {
        int s = src[e], d = dst[e];
        int b = d >> 5;
        int pos = atomicAdd(&scur[(shard * NB + b) * CURSTRIDE], 1);
        if (pos < SCAP)
            recs[((size_t)shard * NB + b) * SCAP + pos] = ((unsigned)s << 5) | (unsigned)(d & 31);
    }
}

__global__ __launch_bounds__(256) void k_build(const unsigned* __restrict__ recs,
                                               const int* __restrict__ scur, int n, int NB,
                                               float* __restrict__ dinv,
                                               int* __restrict__ rp, int* __restrict__ re,
                                               int* __restrict__ col) {
    __shared__ unsigned lrec[BCAP];
    __shared__ int c32[NPB], x32[NPB], cur32[NPB];
    const int b = blockIdx.x;
    const int t = threadIdx.x;
    const size_t base = (size_t)b * BCAP;

    int cp[NSHARD + 1];
    cp[0] = 0;
#pragma unroll
    for (int s = 0; s < NSHARD; ++s) {
        int c = scur[(s * NB + b) * CURSTRIDE];
        c = (c < SCAP) ? c : SCAP;
        cp[s + 1] = cp[s] + c;
    }
    const int cnt = (cp[NSHARD] < BCAP) ? cp[NSHARD] : BCAP;

#pragma unroll
    for (int s = 0; s < NSHARD; ++s) {
        const unsigned* seg = recs + ((size_t)s * NB + b) * SCAP;
        const int c = cp[s + 1] - cp[s];
        for (int k = t; k < c; k += 256) {
            int o = cp[s] + k;
            if (o < BCAP) lrec[o] = seg[k];
        }
    }
    if (t < NPB) c32[t] = 0;
    __syncthreads();
    for (int k = t; k < cnt; k += 256) atomicAdd(&c32[lrec[k] & (NPB - 1)], 1);
    __syncthreads();
    if (t == 0) {
        int run = 0;
        for (int j = 0; j < NPB; ++j) { x32[j] = run; run += c32[j]; }
    }
    __syncthreads();
    if (t < NPB) {
        int node = b * NPB + t;
        if (node < n) {
            dinv[node] = rsqrtf((float)c32[t] + 1.0f);  // +1 self loop
            rp[node] = (int)base + x32[t];
            re[node] = (int)base + x32[t] + c32[t];
        }
        cur32[t] = x32[t];
    }
    __syncthreads();
    for (int k = t; k < cnt; k += 256) {
        unsigned r = lrec[k];
        int node = r & (NPB - 1);
        int slot = atomicAdd(&cur32[node], 1);
        col[base + slot] = (int)(r >> 5);
    }
}

// ---------------- W prep (merged): W[k][c] f32 -> Wt_hi/Wt_lo [c][k] bf16 ----------------

__global__ void k_wsplit_all(const float* __restrict__ W1, const float* __restrict__ W2,
                             const float* __restrict__ W3,
                             unsigned short* __restrict__ W1h, unsigned short* __restrict__ W1l,
                             unsigned short* __restrict__ W2h, unsigned short* __restrict__ W2l,
                             unsigned short* __restrict__ W3h, unsigned short* __restrict__ W3l) {
    int idx = blockIdx.x * 256 + threadIdx.x;
    const float* W;
    unsigned short *Wh, *Wl;
    int C;
    if (idx < 16384) { W = W1; Wh = W1h; Wl = W1l; C = 128; }
    else if (idx < 32768) { idx -= 16384; W = W2; Wh = W2h; Wl = W2l; C = 128; }
    else if (idx < 40960) { idx -= 32768; W = W3; Wh = W3h; Wl = W3l; C = 64; }
    else return;
    int c = idx >> 7;
    int k = idx & 127;
    float a = W[k * C + c];
    unsigned short h = f2bf(a);
    float hf = __uint_as_float((unsigned int)h << 16);
    Wh[idx] = h;
    Wl[idx] = f2bf(a - hf);
}

// ---------------- MFMA GEMM (layer 1 only): h1[n,128] = x[n,128] @ W1 ----------------
// A f32, hi/lo split, D = Ah*Wh + Al*Wh + Ah*Wl (3 MFMA), bf16 out

__global__ __launch_bounds__(512, 4) void k_gemm_l1(
    const float* __restrict__ A, const unsigned short* __restrict__ Wt_hi,
    const unsigned short* __restrict__ Wt_lo, unsigned short* __restrict__ hout,
    int ntiles) {
    __shared__ unsigned short Ah[32 * 128];
    __shared__ unsigned short Al[32 * 128];
    const int t = threadIdx.x;
    const int wave = t >> 6, lane = t & 63;
    const int l15 = lane & 15, l4 = lane >> 4;
    const int cb = wave;

    bf16x8 wh[4], wl[4];
    {
        const int c = cb * 16 + l15;
#pragma unroll
        for (int kk = 0; kk < 4; ++kk) {
            const int off = c * 128 + kk * 32 + l4 * 8;  // elements
            wh[kk] = *(const bf16x8*)&Wt_hi[off];
            wl[kk] = *(const bf16x8*)&Wt_lo[off];
        }
    }

    const int srow = t >> 4;
    const int sk0 = (t & 15) * 8;
    const int sboff = (srow * 256 + sk0 * 2) ^ ((srow & 7) << 4);

    for (int mt = blockIdx.x; mt < ntiles; mt += gridDim.x) {
        __syncthreads();
        {
            const float* src = A + ((size_t)mt * 32 + srow) * 128 + sk0;
            float4 a0 = *(const float4*)src;
            float4 a1 = *(const float4*)(src + 4);
            float av[8] = {a0.x, a0.y, a0.z, a0.w, a1.x, a1.y, a1.z, a1.w};
            bf16x8 hv, lv;
#pragma unroll
            for (int j = 0; j < 8; ++j) {
                unsigned short h = f2bf(av[j]);
                float hf = __uint_as_float((unsigned int)h << 16);
                hv[j] = (short)h;
                lv[j] = (short)f2bf(av[j] - hf);
            }
            *(bf16x8*)((char*)Ah + sboff) = hv;
            *(bf16x8*)((char*)Al + sboff) = lv;
        }
        __syncthreads();

        f32x4 acc0 = {0.f, 0.f, 0.f, 0.f};
        f32x4 acc1 = {0.f, 0.f, 0.f, 0.f};
        const int row0 = l15;
        const int xo = (l15 & 7) << 4;
#pragma unroll
        for (int kk = 0; kk < 4; ++kk) {
            const int off = kk * 64 + l4 * 16;  // bytes
            bf16x8 a0h = *(const bf16x8*)((const char*)Ah + ((row0 * 256 + off) ^ xo));
            bf16x8 a1h = *(const bf16x8*)((const char*)Ah + (((16 + l15) * 256 + off) ^ xo));
            bf16x8 a0l = *(const bf16x8*)((const char*)Al + ((row0 * 256 + off) ^ xo));
            bf16x8 a1l = *(const bf16x8*)((const char*)Al + (((16 + l15) * 256 + off) ^ xo));
            acc0 = __builtin_amdgcn_mfma_f32_16x16x32_bf16(a0h, wh[kk], acc0, 0, 0, 0);
            acc1 = __builtin_amdgcn_mfma_f32_16x16x32_bf16(a1h, wh[kk], acc1, 0, 0, 0);
            acc0 = __builtin_amdgcn_mfma_f32_16x16x32_bf16(a0l, wh[kk], acc0, 0, 0, 0);
            acc1 = __builtin_amdgcn_mfma_f32_16x16x32_bf16(a1l, wh[kk], acc1, 0, 0, 0);
            acc0 = __builtin_amdgcn_mfma_f32_16x16x32_bf16(a0h, wl[kk], acc0, 0, 0, 0);
            acc1 = __builtin_amdgcn_mfma_f32_16x16x32_bf16(a1h, wl[kk], acc1, 0, 0, 0);
        }

        const size_t rbase = (size_t)mt * 32;
        const int c = cb * 16 + l15;
#pragma unroll
        for (int q = 0; q < 4; ++q) {
            hout[(rbase + (size_t)(l4 * 4 + q)) * 128 + c] = f2bf(acc0[q]);
            hout[(rbase + (size_t)(16 + l4 * 4 + q)) * 128 + c] = f2bf(acc1[q]);
        }
    }
}

// ---------------- Fused aggregate + GEMM (layers 2,3) ----------------
// Block = bucket b (32 nodes). Phase 1: wave w aggregates nodes {4w..4w+3}
// (bias+ReLU, f32) and stores bf16 rows into swizzled LDS A-tile.
// Phase 2: A[32,128] @ W[128,OUTD] (2-MFMA exact-bf16), bf16 out.

template <int OUTD>
__global__ __launch_bounds__(512, 4) void k_fused_agg_gemm(
    const unsigned int* __restrict__ hb,  // [n,64] bf16x2
    const int* __restrict__ rp, const int* __restrict__ re,
    const int* __restrict__ col, const float* __restrict__ dinv,
    const float* __restrict__ bias, const unsigned short* __restrict__ Wt_hi,
    const unsigned short* __restrict__ Wt_lo, unsigned short* __restrict__ hout,
    int n) {
    __shared__ unsigned short At[32 * 128];
    const int t = threadIdx.x;
    const int wave = t >> 6, lane = t & 63;
    const int l15 = lane & 15, l4 = lane >> 4;
    const int b = blockIdx.x;

    // ---- phase 1: aggregate 4 nodes per wave ----
    float2 bb = ((const float2*)bias)[lane];
#pragma unroll
    for (int j = 0; j < 4; ++j) {
        const int row = wave * 4 + j;
        const int i = b * NPB + row;
        float acc0 = 0.f, acc1 = 0.f;
        if (i < n) {
            const float di = dinv[i];
            unsigned int self = hb[(size_t)i * 64 + lane];
            acc0 = bb.x + di * di * bflo(self);
            acc1 = bb.y + di * di * bfhi(self);
            int e = rp[i];
            const int e1 = re[i];
            for (; e + 4 <= e1; e += 4) {
                int s0 = col[e], s1 = col[e + 1], s2 = col[e + 2], s3 = col[e + 3];
                float w0 = dinv[s0] * di, w1 = dinv[s1] * di;
                float w2 = dinv[s2] * di, w3 = dinv[s3] * di;
                unsigned int v0 = hb[(size_t)s0 * 64 + lane];
                unsigned int v1 = hb[(size_t)s1 * 64 + lane];
                unsigned int v2 = hb[(size_t)s2 * 64 + lane];
                unsigned int v3 = hb[(size_t)s3 * 64 + lane];
                acc0 += w0 * bflo(v0); acc1 += w0 * bfhi(v0);
                acc0 += w1 * bflo(v1); acc1 += w1 * bfhi(v1);
                acc0 += w2 * bflo(v2); acc1 += w2 * bfhi(v2);
                acc0 += w3 * bflo(v3); acc1 += w3 * bfhi(v3);
            }
            for (; e < e1; ++e) {
                int s = col[e];
                float w = dinv[s] * di;
                unsigned int v = hb[(size_t)s * 64 + lane];
                acc0 += w * bflo(v); acc1 += w * bfhi(v);
            }
            acc0 = fmaxf(acc0, 0.0f);
            acc1 = fmaxf(acc1, 0.0f);
        }
        // store 2 bf16 (features 2*lane, 2*lane+1) into swizzled LDS row
        unsigned int pk = (unsigned)f2bf(acc0) | ((unsigned)f2bf(acc1) << 16);
        *(unsigned int*)((char*)At + ((row * 256 + lane * 4) ^ ((row & 7) << 4))) = pk;
    }

    // ---- W fragments (loaded after phase 1 to cut live range) ----
    const int cb = (OUTD == 128) ? wave : (wave & 3);
    const int s0r = (OUTD == 128) ? 0 : (wave >> 2);
    bf16x8 wh[4], wl[4];
    {
        const int c = cb * 16 + l15;
#pragma unroll
        for (int kk = 0; kk < 4; ++kk) {
            const int off = c * 128 + kk * 32 + l4 * 8;  // elements
            wh[kk] = *(const bf16x8*)&Wt_hi[off];
            wl[kk] = *(const bf16x8*)&Wt_lo[off];
        }
    }
    __syncthreads();

    // ---- phase 2: MFMA ----
    f32x4 acc0 = {0.f, 0.f, 0.f, 0.f};
    f32x4 acc1 = {0.f, 0.f, 0.f, 0.f};
    const int row0 = s0r * 16 + l15;
    const int xo = (l15 & 7) << 4;
#pragma unroll
    for (int kk = 0; kk < 4; ++kk) {
        const int off = kk * 64 + l4 * 16;  // bytes
        bf16x8 a0 = *(const bf16x8*)((const char*)At + ((row0 * 256 + off) ^ xo));
        if (OUTD == 128) {
            bf16x8 a1 = *(const bf16x8*)((const char*)At + (((16 + l15) * 256 + off) ^ xo));
            acc0 = __builtin_amdgcn_mfma_f32_16x16x32_bf16(a0, wh[kk], acc0, 0, 0, 0);
            acc1 = __builtin_amdgcn_mfma_f32_16x16x32_bf16(a1, wh[kk], acc1, 0, 0, 0);
            acc0 = __builtin_amdgcn_mfma_f32_16x16x32_bf16(a0, wl[kk], acc0, 0, 0, 0);
            acc1 = __builtin_amdgcn_mfma_f32_16x16x32_bf16(a1, wl[kk], acc1, 0, 0, 0);
        } else {
            acc0 = __builtin_amdgcn_mfma_f32_16x16x32_bf16(a0, wh[kk], acc0, 0, 0, 0);
            acc0 = __builtin_amdgcn_mfma_f32_16x16x32_bf16(a0, wl[kk], acc0, 0, 0, 0);
        }
    }

    const size_t rbase = (size_t)b * NPB;
    const int c = cb * 16 + l15;
#pragma unroll
    for (int q = 0; q < 4; ++q) {
        size_t r0 = rbase + (size_t)(s0r * 16 + l4 * 4 + q);
        if (r0 < (size_t)n) hout[r0 * OUTD + c] = f2bf(acc0[q]);
        if (OUTD == 128) {
            size_t r1 = rbase + (size_t)(16 + l4 * 4 + q);
            if (r1 < (size_t)n) hout[r1 * OUTD + c] = f2bf(acc1[q]);
        }
    }
}

// ---------------- Aggregate (64-dim, bf16 h3): half-wave per node, f32 out ----------------

__global__ void k_agg64_bf16(const unsigned int* __restrict__ hb,  // [n,32] bf16x2
                             const int* __restrict__ rp, const int* __restrict__ re,
                             const int* __restrict__ col, const float* __restrict__ dinv,
                             const float* __restrict__ b, float2* __restrict__ out, int n) {
    const int t = threadIdx.x;
    const int i = blockIdx.x * 8 + (t >> 5);
    const int ln = t & 31;
    if (i >= n) return;
    const float di = dinv[i];
    unsigned int self = hb[(size_t)i * 32 + ln];
    float2 bb = ((const float2*)b)[ln];
    float acc0 = bb.x + di * di * bflo(self);
    float acc1 = bb.y + di * di * bfhi(self);
    int e = rp[i];
    const int e1 = re[i];
    for (; e + 4 <= e1; e += 4) {
        int s0 = col[e], s1 = col[e + 1], s2 = col[e + 2], s3 = col[e + 3];
        float w0 = dinv[s0] * di, w1 = dinv[s1] * di;
        float w2 = dinv[s2] * di, w3 = dinv[s3] * di;
        unsigned int v0 = hb[(size_t)s0 * 32 + ln];
        unsigned int v1 = hb[(size_t)s1 * 32 + ln];
        unsigned int v2 = hb[(size_t)s2 * 32 + ln];
        unsigned int v3 = hb[(size_t)s3 * 32 + ln];
        acc0 += w0 * bflo(v0); acc1 += w0 * bfhi(v0);
        acc0 += w1 * bflo(v1); acc1 += w1 * bfhi(v1);
        acc0 += w2 * bflo(v2); acc1 += w2 * bfhi(v2);
        acc0 += w3 * bflo(v3); acc1 += w3 * bfhi(v3);
    }
    for (; e < e1; ++e) {
        int s = col[e];
        float w = dinv[s] * di;
        unsigned int v = hb[(size_t)s * 32 + ln];
        acc0 += w * bflo(v); acc1 += w * bfhi(v);
    }
    out[(size_t)i * 32 + ln] = make_float2(acc0, acc1);
}

// ---------------- launch ----------------

extern "C" void kernel_launch(void* const* d_in, const int* in_sizes, int n_in,
                              void* d_out, int out_size, void* d_ws, size_t ws_size,
                              hipStream_t stream) {
    const float* x  = (const float*)d_in[0];
    const int*   ei = (const int*)d_in[1];
    const float* W1 = (const float*)d_in[2];
    const float* b1 = (const float*)d_in[3];
    const float* W2 = (const float*)d_in[4];
    const float* b2 = (const float*)d_in[5];
    const float* W3 = (const float*)d_in[6];
    const float* b3 = (const float*)d_in[7];
    float* out = (float*)d_out;

    const int n = in_sizes[0] / 128;
    const int E = in_sizes[1] / 2;
    const int* srcA = ei;
    const int* dstA = ei + E;
    const int NB = (n + NPB - 1) / NPB;  // 3125 for n=100000

    char* ws = (char*)d_ws;
    size_t off = 0;
    auto alloc = [&](size_t bytes) -> void* {
        off = (off + 255) & ~(size_t)255;
        void* p = ws + off;
        off += bytes;
        return p;
    };

    void*  h1   = alloc((size_t)n * 128 * 2);   // bf16 [n,128]; later h3 [n,64] overlays
    void*  h2   = alloc((size_t)n * 128 * 2);   // bf16 [n,128]; recs overlays (16MB < 25.6MB)
    unsigned* recs = (unsigned*)h2;
    float* dinv = (float*)alloc((size_t)n * 4);
    int*   rp   = (int*)alloc((size_t)n * 4);
    int*   re   = (int*)alloc((size_t)n * 4);
    int*   scur = (int*)alloc((size_t)NSHARD * NB * CURSTRIDE * 4);
    int*   col  = (int*)alloc((size_t)NB * BCAP * 4);
    unsigned short* W1h = (unsigned short*)alloc(128 * 128 * 2);
    unsigned short* W1l = (unsigned short*)alloc(128 * 128 * 2);
    unsigned short* W2h = (unsigned short*)alloc(128 * 128 * 2);
    unsigned short* W2l = (unsigned short*)alloc(128 * 128 * 2);
    unsigned short* W3h = (unsigned short*)alloc(64 * 128 * 2);
    unsigned short* W3l = (unsigned short*)alloc(64 * 128 * 2);

    // ---- CSR build (sharded 2-pass bucketed) ----
    hipMemsetAsync(scur, 0, (size_t)NSHARD * NB * CURSTRIDE * 4, stream);
    k_bin<<<(E + 255) / 256, 256, 0, stream>>>(srcA, dstA, E, NB, scur, recs);
    k_build<<<NB, 256, 0, stream>>>(recs, scur, n, NB, dinv, rp, re, col);

    k_wsplit_all<<<160, 256, 0, stream>>>(W1, W2, W3, W1h, W1l, W2h, W2l, W3h, W3l);

    const int ntiles = n / 32;  // 3125

    // layer 1: h1(bf16) = x @ W1
    k_gemm_l1<<<1024, 512, 0, stream>>>(x, W1h, W1l, (unsigned short*)h1, ntiles);
    // layer 2 fused: h2 = relu(Ahat*h1 + b1) @ W2
    k_fused_agg_gemm<128><<<NB, 512, 0, stream>>>((const unsigned int*)h1, rp, re, col,
                                                  dinv, b1, W2h, W2l,
                                                  (unsigned short*)h2, n);
    // layer 3 fused: h3 = relu(Ahat*h2 + b2) @ W3   (h3 overlays h1)
    k_fused_agg_gemm<64><<<NB, 512, 0, stream>>>((const unsigned int*)h2, rp, re, col,
                                                 dinv, b2, W3h, W3l,
                                                 (unsigned short*)h1, n);
    // final aggregate: out = Ahat*h3 + b3 (f32)
    k_agg64_bf16<<<(n + 7) / 8, 256, 0, stream>>>((const unsigned int*)h1, rp, re, col,
                                                  dinv, b3, (float2*)out, n);
}

// Round 12
// 386.814 us; speedup vs baseline: 1.1204x; 1.1204x over previous
//
#include <hip/hip_runtime.h>
#include <hip/hip_bf16.h>

typedef __attribute__((ext_vector_type(8))) short bf16x8;
typedef __attribute__((ext_vector_type(4))) float f32x4;

#define NPB 32          // nodes per bucket (dst>>5)
#define BCAP 768        // total record capacity per bucket in k_build LDS (~512 +11 sigma)
#define NSHARD 8        // write shards (~XCDs)
#define SCAP 160        // per-(shard,bucket) capacity (load ~64, +12 sigma)
#define CURSTRIDE 16    // ints: one cursor per 64B line
#define GEMM_BLOCKS 1024

// ---------------- helpers ----------------

static __device__ __forceinline__ unsigned short f2bf(float f) {
    unsigned int u = __float_as_uint(f);
    unsigned int r = (u + 0x7fffu + ((u >> 16) & 1u)) >> 16;  // RNE
    return (unsigned short)r;
}
static __device__ __forceinline__ float bflo(unsigned int v) {
    return __uint_as_float(v << 16);
}
static __device__ __forceinline__ float bfhi(unsigned int v) {
    return __uint_as_float(v & 0xffff0000u);
}

// ---------------- Launch A: gemm_l1 (blocks <GEMM_BLOCKS) + bin (rest) ----------------
// gemm_l1: h1[n,128](bf16) = x[n,128](f32) @ W1; A hi/lo split in LDS, W1 split in regs.
// bin: scatter edges into per-(shard,bucket) segments; shard ~ XCD for full-line writebacks.

__global__ __launch_bounds__(512, 4) void k_l1_bin(
    const float* __restrict__ x, const float* __restrict__ W1,
    unsigned short* __restrict__ h1, int ntiles,
    const int* __restrict__ src, const int* __restrict__ dst, int E,
    int NB, int* __restrict__ scur, unsigned* __restrict__ recs) {
    __shared__ unsigned short Ah[32 * 128];
    __shared__ unsigned short Al[32 * 128];
    const int t = threadIdx.x;

    if (blockIdx.x >= GEMM_BLOCKS) {
        // ---- bin path ----
        const int bid = blockIdx.x - GEMM_BLOCKS;
        const int e = bid * 512 + t;
        const int shard = bid & (NSHARD - 1);
        if (e < E) {
            int s = src[e], d = dst[e];
            int b = d >> 5;
            int pos = atomicAdd(&scur[(shard * NB + b) * CURSTRIDE], 1);
            if (pos < SCAP)
                recs[((size_t)shard * NB + b) * SCAP + pos] =
                    ((unsigned)s << 5) | (unsigned)(d & 31);
        }
        return;
    }

    // ---- gemm_l1 path ----
    const int wave = t >> 6, lane = t & 63;
    const int l15 = lane & 15, l4 = lane >> 4;
    const int cb = wave;

    // W1 fragments: load f32, split hi/lo in regs (same ops as k_wsplit)
    bf16x8 wh[4], wl[4];
    {
        const int c = cb * 16 + l15;
#pragma unroll
        for (int kk = 0; kk < 4; ++kk) {
#pragma unroll
            for (int j = 0; j < 8; ++j) {
                float a = W1[(kk * 32 + l4 * 8 + j) * 128 + c];
                unsigned short hh = f2bf(a);
                wh[kk][j] = (short)hh;
                wl[kk][j] = (short)f2bf(a - __uint_as_float((unsigned)hh << 16));
            }
        }
    }

    const int srow = t >> 4;
    const int sk0 = (t & 15) * 8;
    const int sboff = (srow * 256 + sk0 * 2) ^ ((srow & 7) << 4);

    for (int mt = blockIdx.x; mt < ntiles; mt += GEMM_BLOCKS) {
        __syncthreads();
        {
            const float* srcp = x + ((size_t)mt * 32 + srow) * 128 + sk0;
            float4 a0 = *(const float4*)srcp;
            float4 a1 = *(const float4*)(srcp + 4);
            float av[8] = {a0.x, a0.y, a0.z, a0.w, a1.x, a1.y, a1.z, a1.w};
            bf16x8 hv, lv;
#pragma unroll
            for (int j = 0; j < 8; ++j) {
                unsigned short h = f2bf(av[j]);
                float hf = __uint_as_float((unsigned int)h << 16);
                hv[j] = (short)h;
                lv[j] = (short)f2bf(av[j] - hf);
            }
            *(bf16x8*)((char*)Ah + sboff) = hv;
            *(bf16x8*)((char*)Al + sboff) = lv;
        }
        __syncthreads();

        f32x4 acc0 = {0.f, 0.f, 0.f, 0.f};
        f32x4 acc1 = {0.f, 0.f, 0.f, 0.f};
        const int row0 = l15;
        const int xo = (l15 & 7) << 4;
#pragma unroll
        for (int kk = 0; kk < 4; ++kk) {
            const int off = kk * 64 + l4 * 16;  // bytes
            bf16x8 a0h = *(const bf16x8*)((const char*)Ah + ((row0 * 256 + off) ^ xo));
            bf16x8 a1h = *(const bf16x8*)((const char*)Ah + (((16 + l15) * 256 + off) ^ xo));
            bf16x8 a0l = *(const bf16x8*)((const char*)Al + ((row0 * 256 + off) ^ xo));
            bf16x8 a1l = *(const bf16x8*)((const char*)Al + (((16 + l15) * 256 + off) ^ xo));
            acc0 = __builtin_amdgcn_mfma_f32_16x16x32_bf16(a0h, wh[kk], acc0, 0, 0, 0);
            acc1 = __builtin_amdgcn_mfma_f32_16x16x32_bf16(a1h, wh[kk], acc1, 0, 0, 0);
            acc0 = __builtin_amdgcn_mfma_f32_16x16x32_bf16(a0l, wh[kk], acc0, 0, 0, 0);
            acc1 = __builtin_amdgcn_mfma_f32_16x16x32_bf16(a1l, wh[kk], acc1, 0, 0, 0);
            acc0 = __builtin_amdgcn_mfma_f32_16x16x32_bf16(a0h, wl[kk], acc0, 0, 0, 0);
            acc1 = __builtin_amdgcn_mfma_f32_16x16x32_bf16(a1h, wl[kk], acc1, 0, 0, 0);
        }

        const size_t rbase = (size_t)mt * 32;
        const int c = cb * 16 + l15;
#pragma unroll
        for (int q = 0; q < 4; ++q) {
            h1[(rbase + (size_t)(l4 * 4 + q)) * 128 + c] = f2bf(acc0[q]);
            h1[(rbase + (size_t)(16 + l4 * 4 + q)) * 128 + c] = f2bf(acc1[q]);
        }
    }
}

// ---------------- Launch B: build (blocks < NB) + wsplit W2/W3 (rest) ----------------

__global__ __launch_bounds__(256) void k_build_ws(
    const unsigned* __restrict__ recs, const int* __restrict__ scur, int n, int NB,
    float* __restrict__ dinv, int* __restrict__ rp, int* __restrict__ re,
    int* __restrict__ col,
    const float* __restrict__ W2, const float* __restrict__ W3,
    unsigned short* __restrict__ W2h, unsigned short* __restrict__ W2l,
    unsigned short* __restrict__ W3h, unsigned short* __restrict__ W3l) {
    const int t = threadIdx.x;

    if (blockIdx.x >= (unsigned)NB) {
        // ---- wsplit path: W2 (16384 elems) then W3 (8192) ----
        int idx = (blockIdx.x - NB) * 256 + t;
        const float* W;
        unsigned short *Wh, *Wl;
        int C;
        if (idx < 16384) { W = W2; Wh = W2h; Wl = W2l; C = 128; }
        else if (idx < 24576) { idx -= 16384; W = W3; Wh = W3h; Wl = W3l; C = 64; }
        else return;
        int c = idx >> 7;
        int k = idx & 127;
        float a = W[k * C + c];
        unsigned short h = f2bf(a);
        Wh[idx] = h;
        Wl[idx] = f2bf(a - __uint_as_float((unsigned int)h << 16));
        return;
    }

    // ---- build path ----
    __shared__ unsigned lrec[BCAP];
    __shared__ int c32[NPB], x32[NPB], cur32[NPB];
    const int b = blockIdx.x;
    const size_t base = (size_t)b * BCAP;

    int cp[NSHARD + 1];
    cp[0] = 0;
#pragma unroll
    for (int s = 0; s < NSHARD; ++s) {
        int c = scur[(s * NB + b) * CURSTRIDE];
        c = (c < SCAP) ? c : SCAP;
        cp[s + 1] = cp[s] + c;
    }
    const int cnt = (cp[NSHARD] < BCAP) ? cp[NSHARD] : BCAP;

#pragma unroll
    for (int s = 0; s < NSHARD; ++s) {
        const unsigned* seg = recs + ((size_t)s * NB + b) * SCAP;
        const int c = cp[s + 1] - cp[s];
        for (int k = t; k < c; k += 256) {
            int o = cp[s] + k;
            if (o < BCAP) lrec[o] = seg[k];
        }
    }
    if (t < NPB) c32[t] = 0;
    __syncthreads();
    for (int k = t; k < cnt; k += 256) atomicAdd(&c32[lrec[k] & (NPB - 1)], 1);
    __syncthreads();
    if (t == 0) {
        int run = 0;
        for (int j = 0; j < NPB; ++j) { x32[j] = run; run += c32[j]; }
    }
    __syncthreads();
    if (t < NPB) {
        int node = b * NPB + t;
        if (node < n) {
            dinv[node] = rsqrtf((float)c32[t] + 1.0f);  // +1 self loop
            rp[node] = (int)base + x32[t];
            re[node] = (int)base + x32[t] + c32[t];
        }
        cur32[t] = x32[t];
    }
    __syncthreads();
    for (int k = t; k < cnt; k += 256) {
        unsigned r = lrec[k];
        int node = r & (NPB - 1);
        int slot = atomicAdd(&cur32[node], 1);
        col[base + slot] = (int)(r >> 5);
    }
}

// ---------------- MFMA GEMM (layers 2,3): A exact bf16, D = A*Wh + A*Wl ----------------

template <int OUTD>
__global__ __launch_bounds__(512, 4) void k_gemm_bf16(
    const unsigned short* __restrict__ A, const unsigned short* __restrict__ Wt_hi,
    const unsigned short* __restrict__ Wt_lo, unsigned short* __restrict__ hout,
    int ntiles) {
    __shared__ unsigned short At[32 * 128];
    const int t = threadIdx.x;
    const int wave = t >> 6, lane = t & 63;
    const int l15 = lane & 15, l4 = lane >> 4;

    const int cb = (OUTD == 128) ? wave : (wave & 3);
    const int s0 = (OUTD == 128) ? 0 : (wave >> 2);

    bf16x8 wh[4], wl[4];
    {
        const int c = cb * 16 + l15;
#pragma unroll
        for (int kk = 0; kk < 4; ++kk) {
            const int off = c * 128 + kk * 32 + l4 * 8;  // elements
            wh[kk] = *(const bf16x8*)&Wt_hi[off];
            wl[kk] = *(const bf16x8*)&Wt_lo[off];
        }
    }

    const int srow = t >> 4;
    const int sk0 = (t & 15) * 8;
    const int sboff = (srow * 256 + sk0 * 2) ^ ((srow & 7) << 4);

    for (int mt = blockIdx.x; mt < ntiles; mt += gridDim.x) {
        __syncthreads();
        {
            const unsigned short* src = A + ((size_t)mt * 32 + srow) * 128 + sk0;
            *(bf16x8*)((char*)At + sboff) = *(const bf16x8*)src;
        }
        __syncthreads();

        f32x4 acc0 = {0.f, 0.f, 0.f, 0.f};
        f32x4 acc1 = {0.f, 0.f, 0.f, 0.f};
        const int row0 = s0 * 16 + l15;
        const int xo = (l15 & 7) << 4;
#pragma unroll
        for (int kk = 0; kk < 4; ++kk) {
            const int off = kk * 64 + l4 * 16;  // bytes
            bf16x8 a0 = *(const bf16x8*)((const char*)At + ((row0 * 256 + off) ^ xo));
            if (OUTD == 128) {
                bf16x8 a1 = *(const bf16x8*)((const char*)At + (((16 + l15) * 256 + off) ^ xo));
                acc0 = __builtin_amdgcn_mfma_f32_16x16x32_bf16(a0, wh[kk], acc0, 0, 0, 0);
                acc1 = __builtin_amdgcn_mfma_f32_16x16x32_bf16(a1, wh[kk], acc1, 0, 0, 0);
                acc0 = __builtin_amdgcn_mfma_f32_16x16x32_bf16(a0, wl[kk], acc0, 0, 0, 0);
                acc1 = __builtin_amdgcn_mfma_f32_16x16x32_bf16(a1, wl[kk], acc1, 0, 0, 0);
            } else {
                acc0 = __builtin_amdgcn_mfma_f32_16x16x32_bf16(a0, wh[kk], acc0, 0, 0, 0);
                acc0 = __builtin_amdgcn_mfma_f32_16x16x32_bf16(a0, wl[kk], acc0, 0, 0, 0);
            }
        }

        const size_t rbase = (size_t)mt * 32;
        const int c = cb * 16 + l15;
#pragma unroll
        for (int q = 0; q < 4; ++q) {
            size_t r0 = rbase + (size_t)(s0 * 16 + l4 * 4 + q);
            hout[r0 * OUTD + c] = f2bf(acc0[q]);
            if (OUTD == 128) {
                size_t r1 = rbase + (size_t)(16 + l4 * 4 + q);
                hout[r1 * OUTD + c] = f2bf(acc1[q]);
            }
        }
    }
}

// ---------------- Aggregate (128-dim, bf16 h -> bf16 out): 1 wave/node ----------------

template <bool RELU>
__global__ void k_agg128_bf16(const unsigned int* __restrict__ hb,  // [n,64] bf16x2
                              const int* __restrict__ rp, const int* __restrict__ re,
                              const int* __restrict__ col, const float* __restrict__ dinv,
                              const float* __restrict__ b, unsigned int* __restrict__ outb,
                              int n) {
    const int i = blockIdx.x;
    const int t = threadIdx.x;  // 0..63
    const float di = dinv[i];
    unsigned int self = hb[(size_t)i * 64 + t];
    float2 bb = ((const float2*)b)[t];
    float acc0 = bb.x + di * di * bflo(self);
    float acc1 = bb.y + di * di * bfhi(self);
    int e = rp[i];
    const int e1 = re[i];
    for (; e + 8 <= e1; e += 8) {
        int s[8];
        float w[8];
        unsigned int v[8];
#pragma unroll
        for (int j = 0; j < 8; ++j) s[j] = col[e + j];
#pragma unroll
        for (int j = 0; j < 8; ++j) { w[j] = dinv[s[j]] * di; v[j] = hb[(size_t)s[j] * 64 + t]; }
#pragma unroll
        for (int j = 0; j < 8; ++j) { acc0 += w[j] * bflo(v[j]); acc1 += w[j] * bfhi(v[j]); }
    }
    for (; e + 4 <= e1; e += 4) {
        int s0 = col[e], s1 = col[e + 1], s2 = col[e + 2], s3 = col[e + 3];
        float w0 = dinv[s0] * di, w1 = dinv[s1] * di;
        float w2 = dinv[s2] * di, w3 = dinv[s3] * di;
        unsigned int v0 = hb[(size_t)s0 * 64 + t];
        unsigned int v1 = hb[(size_t)s1 * 64 + t];
        unsigned int v2 = hb[(size_t)s2 * 64 + t];
        unsigned int v3 = hb[(size_t)s3 * 64 + t];
        acc0 += w0 * bflo(v0); acc1 += w0 * bfhi(v0);
        acc0 += w1 * bflo(v1); acc1 += w1 * bfhi(v1);
        acc0 += w2 * bflo(v2); acc1 += w2 * bfhi(v2);
        acc0 += w3 * bflo(v3); acc1 += w3 * bfhi(v3);
    }
    for (; e < e1; ++e) {
        int s = col[e];
        float w = dinv[s] * di;
        unsigned int v = hb[(size_t)s * 64 + t];
        acc0 += w * bflo(v); acc1 += w * bfhi(v);
    }
    if (RELU) { acc0 = fmaxf(acc0, 0.0f); acc1 = fmaxf(acc1, 0.0f); }
    outb[(size_t)i * 64 + t] = (unsigned)f2bf(acc0) | ((unsigned)f2bf(acc1) << 16);
}

// ---------------- Aggregate (64-dim, bf16 h3): half-wave per node, f32 out ----------------

__global__ void k_agg64_bf16(const unsigned int* __restrict__ hb,  // [n,32] bf16x2
                             const int* __restrict__ rp, const int* __restrict__ re,
                             const int* __restrict__ col, const float* __restrict__ dinv,
                             const float* __restrict__ b, float2* __restrict__ out, int n) {
    const int t = threadIdx.x;
    const int i = blockIdx.x * 8 + (t >> 5);
    const int ln = t & 31;
    if (i >= n) return;
    const float di = dinv[i];
    unsigned int self = hb[(size_t)i * 32 + ln];
    float2 bb = ((const float2*)b)[ln];
    float acc0 = bb.x + di * di * bflo(self);
    float acc1 = bb.y + di * di * bfhi(self);
    int e = rp[i];
    const int e1 = re[i];
    for (; e + 8 <= e1; e += 8) {
        int s[8];
        float w[8];
        unsigned int v[8];
#pragma unroll
        for (int j = 0; j < 8; ++j) s[j] = col[e + j];
#pragma unroll
        for (int j = 0; j < 8; ++j) { w[j] = dinv[s[j]] * di; v[j] = hb[(size_t)s[j] * 32 + ln]; }
#pragma unroll
        for (int j = 0; j < 8; ++j) { acc0 += w[j] * bflo(v[j]); acc1 += w[j] * bfhi(v[j]); }
    }
    for (; e + 4 <= e1; e += 4) {
        int s0 = col[e], s1 = col[e + 1], s2 = col[e + 2], s3 = col[e + 3];
        float w0 = dinv[s0] * di, w1 = dinv[s1] * di;
        float w2 = dinv[s2] * di, w3 = dinv[s3] * di;
        unsigned int v0 = hb[(size_t)s0 * 32 + ln];
        unsigned int v1 = hb[(size_t)s1 * 32 + ln];
        unsigned int v2 = hb[(size_t)s2 * 32 + ln];
        unsigned int v3 = hb[(size_t)s3 * 32 + ln];
        acc0 += w0 * bflo(v0); acc1 += w0 * bfhi(v0);
        acc0 += w1 * bflo(v1); acc1 += w1 * bfhi(v1);
        acc0 += w2 * bflo(v2); acc1 += w2 * bfhi(v2);
        acc0 += w3 * bflo(v3); acc1 += w3 * bfhi(v3);
    }
    for (; e < e1; ++e) {
        int s = col[e];
        float w = dinv[s] * di;
        unsigned int v = hb[(size_t)s * 32 + ln];
        acc0 += w * bflo(v); acc1 += w * bfhi(v);
    }
    out[(size_t)i * 32 + ln] = make_float2(acc0, acc1);
}

// ---------------- launch ----------------

extern "C" void kernel_launch(void* const* d_in, const int* in_sizes, int n_in,
                              void* d_out, int out_size, void* d_ws, size_t ws_size,
                              hipStream_t stream) {
    const float* x  = (const float*)d_in[0];
    const int*   ei = (const int*)d_in[1];
    const float* W1 = (const float*)d_in[2];
    const float* b1 = (const float*)d_in[3];
    const float* W2 = (const float*)d_in[4];
    const float* b2 = (const float*)d_in[5];
    const float* W3 = (const float*)d_in[6];
    const float* b3 = (const float*)d_in[7];
    float* out = (float*)d_out;

    const int n = in_sizes[0] / 128;
    const int E = in_sizes[1] / 2;
    const int* srcA = ei;
    const int* dstA = ei + E;
    const int NB = (n + NPB - 1) / NPB;  // 3125 for n=100000

    char* ws = (char*)d_ws;
    size_t off = 0;
    auto alloc = [&](size_t bytes) -> void* {
        off = (off + 255) & ~(size_t)255;
        void* p = ws + off;
        off += bytes;
        return p;
    };

    void*  h    = alloc((size_t)n * 128 * 2);   // bf16 [n,128] (h1/h3)
    void*  agg  = alloc((size_t)n * 128 * 2);   // bf16 [n,128] (agg/h2); recs overlays
    unsigned* recs = (unsigned*)agg;            // 16MB <= 25.6MB, dead before agg written
    float* dinv = (float*)alloc((size_t)n * 4);
    int*   rp   = (int*)alloc((size_t)n * 4);
    int*   re   = (int*)alloc((size_t)n * 4);
    int*   scur = (int*)alloc((size_t)NSHARD * NB * CURSTRIDE * 4);
    int*   col  = (int*)alloc((size_t)NB * BCAP * 4);
    unsigned short* W2h = (unsigned short*)alloc(128 * 128 * 2);
    unsigned short* W2l = (unsigned short*)alloc(128 * 128 * 2);
    unsigned short* W3h = (unsigned short*)alloc(64 * 128 * 2);
    unsigned short* W3l = (unsigned short*)alloc(64 * 128 * 2);

    const int ntiles = n / 32;  // 3125
    const int binBlocks = (E + 511) / 512;

    hipMemsetAsync(scur, 0, (size_t)NSHARD * NB * CURSTRIDE * 4, stream);
    // Launch A: gemm_l1 (h1 = x@W1, W1 split inline) || bin
    k_l1_bin<<<GEMM_BLOCKS + binBlocks, 512, 0, stream>>>(
        x, W1, (unsigned short*)h, ntiles, srcA, dstA, E, NB, scur, recs);
    // Launch B: build || wsplit(W2,W3)
    k_build_ws<<<NB + 96, 256, 0, stream>>>(recs, scur, n, NB, dinv, rp, re, col,
                                            W2, W3, W2h, W2l, W3h, W3l);

    // layer 1 aggregate: agg(bf16) = relu(Ahat*h1 + b1)
    k_agg128_bf16<true><<<n, 64, 0, stream>>>((const unsigned int*)h, rp, re, col, dinv, b1,
                                              (unsigned int*)agg, n);
    // layer 2 GEMM + aggregate
    k_gemm_bf16<128><<<1024, 512, 0, stream>>>((const unsigned short*)agg, W2h, W2l,
                                               (unsigned short*)h, ntiles);
    k_agg128_bf16<true><<<n, 64, 0, stream>>>((const unsigned int*)h, rp, re, col, dinv, b2,
                                              (unsigned int*)agg, n);
    // layer 3 GEMM (128->64) + final aggregate (f32 out)
    k_gemm_bf16<64><<<1024, 512, 0, stream>>>((const unsigned short*)agg, W3h, W3l,
                                              (unsigned short*)h, ntiles);
    k_agg64_bf16<<<(n + 7) / 8, 256, 0, stream>>>((const unsigned int*)h, rp, re, col, dinv,
                                                  b3, (float2*)out, n);
}